// Round 2
// baseline (525.380 us; speedup 1.0000x reference)
//
#include <hip/hip_runtime.h>
#include <hip/hip_bf16.h>

#define NANCH 202500
#define PRE_NMS 6000
#define POST_NMS 300
#define CAP 8192
#define SORT_SZ 8192
#define NBUCK 16384
#define BSHIFT 18
#define IOU_TH 0.7f
#define MIN_SIZE 0.016f
#define TB_PAD 6016      // topbox padded to chunk multiple of 64

// ---------------- shared decode / key helpers ---------------------------
__device__ inline float4 decode_box(const float* __restrict__ loc,
                                    const float* __restrict__ anc, int i) {
    float4 a = ((const float4*)anc)[i];
    float4 t = ((const float4*)loc)[i];
    float pw = a.z - a.x, ph = a.w - a.y;
    float pcx = (a.x + a.z) * 0.5f, pcy = (a.y + a.w) * 0.5f;
    float cx = t.x * pw + pcx, cy = t.y * ph + pcy;
    float w = expf(t.z) * pw, h = expf(t.w) * ph;
    float x1 = fminf(fmaxf(cx - 0.5f * w, 0.f), 1.f);
    float y1 = fminf(fmaxf(cy - 0.5f * h, 0.f), 1.f);
    float x2 = fminf(fmaxf(cx + 0.5f * w, 0.f), 1.f);
    float y2 = fminf(fmaxf(cy + 0.5f * h, 0.f), 1.f);
    return make_float4(x1, y1, x2, y2);
}

__device__ inline unsigned make_key(const float* __restrict__ cls,
                                    const float* __restrict__ loc,
                                    const float* __restrict__ anc, int i) {
    float2 c = ((const float2*)cls)[i];
    float d = c.y - c.x;                       // monotone proxy for softmax[:,1]
    float4 b = decode_box(loc, anc, i);
    bool valid = ((b.z - b.x) >= MIN_SIZE) && ((b.w - b.y) >= MIN_SIZE);
    unsigned ib = __float_as_uint(d);
    unsigned u = (ib & 0x80000000u) ? ~ib : (ib | 0x80000000u);  // monotonic key
    return valid ? u : 0u;                     // invalid -> below everything
}

// ---------------- K1: histogram of 14-bit buckets ------------------------
__global__ __launch_bounds__(256) void k_score(const float* __restrict__ cls,
                                               const float* __restrict__ loc,
                                               const float* __restrict__ anc,
                                               unsigned* __restrict__ hist, int n) {
    int i = blockIdx.x * blockDim.x + threadIdx.x;
    if (i >= n) return;
    unsigned u = make_key(cls, loc, anc, i);
    atomicAdd(&hist[u >> BSHIFT], 1u);
}

// ---------------- K2: find boundary bucket B (rank 6000 from top) -------
__global__ __launch_bounds__(1024) void k_findb(const unsigned* __restrict__ hist,
                                                unsigned* __restrict__ meta) {
    __shared__ unsigned ps[1024];
    int t = threadIdx.x;
    int base = t * (NBUCK / 1024);
    unsigned local = 0;
    for (int b = 0; b < NBUCK / 1024; b++) local += hist[base + b];
    ps[t] = local;
    __syncthreads();
    // suffix-inclusive scan: ps[t] = sum_{t' >= t} local[t']
    for (int off = 1; off < 1024; off <<= 1) {
        unsigned add = (t + off < 1024) ? ps[t + off] : 0u;
        __syncthreads();
        ps[t] += add;
        __syncthreads();
    }
    unsigned incl = ps[t];
    unsigned excl = incl - local;              // strictly-above-chunk count
    if (incl >= (unsigned)PRE_NMS && excl < (unsigned)PRE_NMS) {
        unsigned cum = excl;
        int B = base;
        for (int b = NBUCK / 1024 - 1; b >= 0; b--) {
            cum += hist[base + b];
            if (cum >= (unsigned)PRE_NMS) { B = base + b; break; }
        }
        meta[0] = (unsigned)B;
    }
}

// ---------------- K3: compact candidates (bucket >= B) ------------------
__global__ __launch_bounds__(256) void k_compact(const float* __restrict__ cls,
                                                 const float* __restrict__ loc,
                                                 const float* __restrict__ anc,
                                                 unsigned* __restrict__ meta,
                                                 unsigned long long* __restrict__ cand,
                                                 int n) {
    int i = blockIdx.x * blockDim.x + threadIdx.x;
    if (i >= n) return;
    unsigned u = make_key(cls, loc, anc, i);
    if ((u >> BSHIFT) >= meta[0]) {
        unsigned p = atomicAdd(&meta[1], 1u);
        if (p < CAP)
            cand[p] = ((unsigned long long)(~u) << 32) | (unsigned)i;  // asc = score desc, idx asc
    }
}

// ---------------- K4: bitonic sort 8192 + gather/decode top boxes -------
__global__ __launch_bounds__(1024) void k_sort(const unsigned long long* __restrict__ cand,
                                               const unsigned* __restrict__ meta,
                                               const float* __restrict__ loc,
                                               const float* __restrict__ anc,
                                               float4* __restrict__ topbox) {
    __shared__ unsigned long long sk[SORT_SZ];   // 64 KB
    int tid = threadIdx.x;
    unsigned C = meta[1];
    if (C > CAP) C = CAP;
    for (int i = tid; i < SORT_SZ; i += 1024)
        sk[i] = (i < (int)C) ? cand[i] : ~0ull;
    __syncthreads();
    for (int k = 2; k <= SORT_SZ; k <<= 1) {
        for (int j = k >> 1; j > 0; j >>= 1) {
            for (int i = tid; i < SORT_SZ; i += 1024) {
                int ixj = i ^ j;
                if (ixj > i) {
                    bool up = ((i & k) == 0);
                    unsigned long long A = sk[i], B = sk[ixj];
                    if ((up && A > B) || (!up && A < B)) { sk[i] = B; sk[ixj] = A; }
                }
            }
            __syncthreads();
        }
    }
    for (int q = tid; q < TB_PAD; q += 1024) {
        unsigned long long kv = sk[q];
        unsigned uu = ~(unsigned)(kv >> 32);
        int idx = (int)(unsigned)kv;
        bool val = (q < PRE_NMS) && (uu != 0u);
        topbox[q] = val ? decode_box(loc, anc, idx)
                        : make_float4(-1.f, -1.f, -1.f, -1.f);   // sentinel = invalid
    }
}

// ---------------- K5: single-wave streaming greedy NMS -> output --------
__global__ __launch_bounds__(64) void k_nms(const float4* __restrict__ topbox,
                                            float* __restrict__ out) {
    int l = threadIdx.x;
    float4 kb[5];                               // kept slot s lives on lane s&63, reg s>>6
    int nk = 0;
    for (int q0 = 0; q0 < TB_PAD && nk < POST_NMS; q0 += 64) {
        float4 myb = topbox[q0 + l];            // coalesced prefetch of 64 candidates
        for (int b = 0; b < 64 && nk < POST_NMS; b++) {
            float4 bb;
            bb.x = __shfl(myb.x, b, 64);
            bb.y = __shfl(myb.y, b, 64);
            bb.z = __shfl(myb.z, b, 64);
            bb.w = __shfl(myb.w, b, 64);
            if (bb.x < 0.f) continue;           // invalid sentinel (uniform)
            float ab = (bb.z - bb.x) * (bb.w - bb.y);
            bool sup = false;
            #pragma unroll
            for (int r = 0; r < 5; r++) {
                int s = r * 64 + l;
                if (s < nk) {
                    float4 kv = kb[r];
                    float ak = (kv.z - kv.x) * (kv.w - kv.y);
                    float lx = fmaxf(bb.x, kv.x), ly = fmaxf(bb.y, kv.y);
                    float rx = fminf(bb.z, kv.z), ry = fminf(bb.w, kv.w);
                    float iw = fmaxf(rx - lx, 0.f), ih = fmaxf(ry - ly, 0.f);
                    float inter = iw * ih;
                    float iou = inter / (ab + ak - inter + 1e-12f);
                    sup |= (iou > IOU_TH);
                }
            }
            if (!__any(sup)) {
                if (l == (nk & 63)) kb[nk >> 6] = bb;
                if (l < 4) {
                    float v = (l == 0) ? bb.x : (l == 1) ? bb.y : (l == 2) ? bb.z : bb.w;
                    out[4 * nk + l] = v;
                }
                nk++;
            }
        }
    }
    for (int t = nk * 4 + l; t < POST_NMS * 4; t += 64) out[t] = 0.f;
}

extern "C" void kernel_launch(void* const* d_in, const int* in_sizes, int n_in,
                              void* d_out, int out_size, void* d_ws, size_t ws_size,
                              hipStream_t stream) {
    const int N = in_sizes[0] / 2;             // 202500
    const float* cls = (const float*)d_in[0];
    const float* loc = (const float*)d_in[1];
    const float* anc = (const float*)d_in[2];
    float* out = (float*)d_out;

    // ws layout (total ~225 KB — stay far inside ws_size; overflow here
    // corrupted the harness's pristine buffers in R1)
    char* ws = (char*)d_ws;
    size_t off = 0;
    auto take = [&](size_t bytes) {
        size_t o = off;
        off += (bytes + 255) & ~(size_t)255;
        return o;
    };
    unsigned* hist           = (unsigned*)(ws + take((size_t)NBUCK * 4));      // 64 KB
    unsigned* meta           = (unsigned*)(ws + take(64));
    unsigned long long* cand = (unsigned long long*)(ws + take((size_t)CAP * 8));   // 64 KB
    float4* topbox           = (float4*)(ws + take((size_t)TB_PAD * 16));      // 94 KB

    hipMemsetAsync(hist, 0, (size_t)NBUCK * 4, stream);
    hipMemsetAsync(meta, 0, 64, stream);

    k_score<<<(N + 255) / 256, 256, 0, stream>>>(cls, loc, anc, hist, N);
    k_findb<<<1, 1024, 0, stream>>>(hist, meta);
    k_compact<<<(N + 255) / 256, 256, 0, stream>>>(cls, loc, anc, meta, cand, N);
    k_sort<<<1, 1024, 0, stream>>>(cand, meta, loc, anc, topbox);
    k_nms<<<1, 64, 0, stream>>>(topbox, out);
}